// Round 7
// baseline (358.271 us; speedup 1.0000x reference)
//
#include <hip/hip_runtime.h>

typedef unsigned short u16;
typedef __attribute__((ext_vector_type(8))) short bf16x8;
typedef __attribute__((ext_vector_type(4))) float f32x4;

#define LOG2E 1.44269504088896340736f

__device__ inline u16 f2b(float f) {
    unsigned int u = __builtin_bit_cast(unsigned int, f);
    unsigned int r = u + 0x7fffu + ((u >> 16) & 1u);
    return (u16)(r >> 16);
}
__device__ inline float b2f(u16 h) {
    unsigned int u = ((unsigned int)h) << 16;
    return __builtin_bit_cast(float, u);
}

#define GLOAD_LDS16(g, l) \
    __builtin_amdgcn_global_load_lds( \
        (const __attribute__((address_space(1))) unsigned int*)(g), \
        (__attribute__((address_space(3))) unsigned int*)(l), 16, 0, 0)

// ---------------- fused cast fp32 -> bf16 for all 5 inputs, 8 elems/thread ----
__global__ __launch_bounds__(256) void cast_all(
    const float* __restrict__ x, const float* __restrict__ wq,
    const float* __restrict__ wk, const float* __restrict__ wv,
    const float* __restrict__ wo, u16* __restrict__ xb,
    u16* __restrict__ wqkvb, u16* __restrict__ wob) {
    long i = ((long)blockIdx.x * 256 + threadIdx.x) * 8;
    const float* s;
    u16* d;
    if (i < 8388608)       { s = x  + i;              d = xb + i; }
    else if (i < 12582912) { s = wq + (i - 8388608);  d = wqkvb + (i - 8388608); }
    else if (i < 13631488) { s = wk + (i - 12582912); d = wqkvb + 4194304 + (i - 12582912); }
    else if (i < 14680064) { s = wv + (i - 13631488); d = wqkvb + 5242880 + (i - 13631488); }
    else                   { s = wo + (i - 14680064); d = wob + (i - 14680064); }
    float4 v0 = *(const float4*)s;
    float4 v1 = *(const float4*)(s + 4);
    ushort4 o0 = make_ushort4(f2b(v0.x), f2b(v0.y), f2b(v0.z), f2b(v0.w));
    ushort4 o1 = make_ushort4(f2b(v1.x), f2b(v1.y), f2b(v1.z), f2b(v1.w));
    *(ushort4*)d = o0;
    *(ushort4*)(d + 4) = o1;
}

// ---------------- fused RoPE (Q+K) and V-transpose in one launch ----------------
__global__ __launch_bounds__(256) void rope_vtrans(
    u16* __restrict__ qkv, u16* __restrict__ VT, float qscale) {
    const int S = 2048, RS = 3072;
    int tid = threadIdx.x;
    if (blockIdx.x < 5120) {
        int idx = blockIdx.x * 256 + tid;   // < 4096*320
        int row = idx / 320;
        int rem = idx - row * 320;
        int head = rem >> 3, chunk = rem & 7;
        int pos = row & 2047;
        int coloff;
        float scale;
        if (head < 32) { coloff = head * 64;               scale = qscale; }
        else           { coloff = 2048 + (head - 32) * 64; scale = 1.0f; }
        u16* p = qkv + (size_t)row * RS + coloff + chunk * 8;
        bf16x8 v = *(bf16x8*)p;
        float t0 = exp2f((float)(chunk * 4) * -0.41524101186092f);
        const float tc[4] = {1.0f, 0.74989420933246f, 0.56234132519035f, 0.42169650342858f};
        float fpos = (float)pos;
        #pragma unroll
        for (int i = 0; i < 4; i++) {
            float f = fpos * (t0 * tc[i]);
            float rev = f * 0.15915494309189535f;  // radians -> revolutions
            rev = rev - floorf(rev);
            float sn = __builtin_amdgcn_sinf(rev);
            float cs = __builtin_amdgcn_cosf(rev);
            float e0 = b2f((u16)v[2 * i]), e1 = b2f((u16)v[2 * i + 1]);
            v[2 * i]     = (short)f2b((e0 * cs - e1 * sn) * scale);
            v[2 * i + 1] = (short)f2b((e1 * cs + e0 * sn) * scale);
        }
        *(bf16x8*)p = v;
    } else {
        int bid = blockIdx.x - 5120;        // 0..511
        int st = bid & 31, g = (bid >> 5) & 7, b = bid >> 8;
        __shared__ u16 T[64 * 72];
        for (int c = tid; c < 512; c += 256) {
            int sr = c >> 3, dc = (c & 7) * 8;
            *(bf16x8*)&T[sr * 72 + dc] =
                *(const bf16x8*)(qkv + ((size_t)b * S + st * 64 + sr) * RS + 2560 + g * 64 + dc);
        }
        __syncthreads();
        for (int c = tid; c < 512; c += 256) {
            int d = c >> 3, sc = (c & 7) * 8;
            bf16x8 o;
            #pragma unroll
            for (int j = 0; j < 8; j++) o[j] = (short)T[(sc + j) * 72 + d];
            *(bf16x8*)(VT + ((size_t)((b * 8 + g) * 64 + d)) * S + st * 64 + sc) = o;
        }
    }
}

// ---------------- GEMM 256x256 8-phase: C[M,N]=A[M,K]*B[N,K]^T --------------
// ROUND-6: split-K support via blockIdx.z (kspl splits). Each z-block handles
// K-range [kz*K/kspl, (kz+1)*K/kspl) and atomicAdd's f32 partials into C
// (harness memsets d_out to 0 before every launch). Mechanism: GEMM2's grid
// was 8x16=128 blocks on 256 CUs at 1 block/CU -> HALF THE MACHINE IDLE for
// its whole duration. kspl=2 -> 256 blocks, full machine. Both z-copies of a
// tile share (m0,n0) and XCD -> same A/B panels stay L2-local.
#define MMAQ(MH, NH, AR, BR) do { \
    __builtin_amdgcn_s_setprio(1); \
    _Pragma("unroll") \
    for (int m2 = 0; m2 < 4; m2++) { \
        _Pragma("unroll") \
        for (int n2 = 0; n2 < 2; n2++) { \
            acc[(MH)*4+m2][(NH)*2+n2] = __builtin_amdgcn_mfma_f32_16x16x32_bf16( \
                AR[m2][0], BR[n2][0], acc[(MH)*4+m2][(NH)*2+n2], 0, 0, 0); \
            acc[(MH)*4+m2][(NH)*2+n2] = __builtin_amdgcn_mfma_f32_16x16x32_bf16( \
                AR[m2][1], BR[n2][1], acc[(MH)*4+m2][(NH)*2+n2], 0, 0, 0); \
        } \
    } \
    __builtin_amdgcn_s_setprio(0); \
} while (0)

#define BAR()    do { __builtin_amdgcn_s_barrier(); \
                      __builtin_amdgcn_sched_barrier(0); } while (0)
#define LGKM0()  do { asm volatile("s_waitcnt lgkmcnt(0)" ::: "memory"); \
                      __builtin_amdgcn_sched_barrier(0); } while (0)
#define VMCNT(n) do { asm volatile("s_waitcnt vmcnt(" #n ")" ::: "memory"); \
                      __builtin_amdgcn_sched_barrier(0); } while (0)

__global__ __launch_bounds__(512) void gemm_bt256(
    const u16* __restrict__ A, const u16* __restrict__ B, void* __restrict__ Cv,
    int M, int N, int K, int c_is_f32, int kspl) {
    __shared__ u16 As[32768];   // [dbuf*2+half][128*64]
    __shared__ u16 Bs[32768];
    const int tid = threadIdx.x;
    const int w = tid >> 6, lane = tid & 63;
    const int ln = lane & 15, quad = lane >> 4;
    const int wr = w >> 2, wc = w & 3;

    // XCD swizzle over the x-y tile grid only; z (K-split) rides along so both
    // splits of a tile land on the same XCD (%8 of dispatch id preserved).
    const int gx = gridDim.x;
    const int nwg = gx * gridDim.y;
    const int bid = blockIdx.y * gx + blockIdx.x;
    const int cpx = nwg >> 3;
    const int swz = (bid & 7) * cpx + (bid >> 3);
    const int m0 = (swz / gx) * 256, n0 = (swz % gx) * 256;

    const int Keff = K / kspl;
    const int koff = blockIdx.z * Keff;

    const int l3 = lane >> 3, l7 = lane & 7;
    const u16* Ast = A + (size_t)(m0 + w * 8 + l3) * K + koff + (l7 ^ l3) * 8;
    const u16* Bst = B + (size_t)(n0 + w * 8 + l3) * K + koff + (l7 ^ l3) * 8;

    auto stageA = [&](int u, int h) {
        const u16* g = Ast + (size_t)(h * 128) * K + u * 64;
        u16* d = As + ((u & 1) * 2 + h) * 8192 + w * 512;
        GLOAD_LDS16(g, d);
        GLOAD_LDS16(g + (size_t)64 * K, d + 4096);
    };
    auto stageB = [&](int u, int h) {
        const u16* g = Bst + (size_t)(h * 128) * K + u * 64;
        u16* d = Bs + ((u & 1) * 2 + h) * 8192 + w * 512;
        GLOAD_LDS16(g, d);
        GLOAD_LDS16(g + (size_t)64 * K, d + 4096);
    };

    const int xs0 = ((quad) ^ (ln & 7)) * 8;
    const int xs1 = ((4 + quad) ^ (ln & 7)) * 8;

    bf16x8 a[4][2], b0[2][2], b1[2][2];
    auto loadA = [&](int u, int mh, bf16x8 (&dst)[4][2]) {
        const u16* base = As + ((u & 1) * 2 + wr) * 8192 + (mh * 64 + ln) * 64;
        #pragma unroll
        for (int m2 = 0; m2 < 4; m2++) {
            dst[m2][0] = *(const bf16x8*)(base + m2 * 1024 + xs0);
            dst[m2][1] = *(const bf16x8*)(base + m2 * 1024 + xs1);
        }
    };
    auto loadB = [&](int u, int nh, bf16x8 (&dst)[2][2]) {
        const u16* base = Bs + ((u & 1) * 2 + (wc >> 1)) * 8192
                        + ((wc & 1) * 64 + nh * 32 + ln) * 64;
        #pragma unroll
        for (int n2 = 0; n2 < 2; n2++) {
            dst[n2][0] = *(const bf16x8*)(base + n2 * 1024 + xs0);
            dst[n2][1] = *(const bf16x8*)(base + n2 * 1024 + xs1);
        }
    };

    f32x4 acc[8][4] = {};
    const int NT = Keff >> 6;

    stageB(0, 0); stageB(0, 1);
    stageA(0, 0); stageA(0, 1);
    stageB(1, 0); stageB(1, 1);
    VMCNT(4);
    BAR();

    for (int u = 0; u < NT; ++u) {
        // ---- P1
        loadA(u, 0, a);
        loadB(u, 0, b0);
        if (u + 1 < NT) stageA(u + 1, 0);
        BAR(); LGKM0();
        MMAQ(0, 0, a, b0);
        BAR();
        // ---- P2
        loadB(u, 1, b1);
        if (u + 1 < NT) stageA(u + 1, 1);
        BAR(); LGKM0();
        MMAQ(0, 1, a, b1);
        BAR();
        // ---- P3
        loadA(u, 1, a);
        if (u + 2 < NT) stageB(u + 2, 0);
        BAR(); LGKM0();
        MMAQ(1, 1, a, b1);
        BAR();
        // ---- P4
        if (u + 2 < NT) stageB(u + 2, 1);
        BAR();
        MMAQ(1, 0, a, b0);
        if (u + 2 < NT)      { VMCNT(4); }
        else if (u + 1 < NT) { VMCNT(0); }
        BAR();
    }

    #pragma unroll
    for (int mi = 0; mi < 8; mi++)
        #pragma unroll
        for (int ni = 0; ni < 4; ni++)
            #pragma unroll
            for (int r = 0; r < 4; r++) {
                int row = m0 + wr * 128 + mi * 16 + quad * 4 + r;
                int col = n0 + wc * 64 + ni * 16 + ln;
                float v = acc[mi][ni][r];
                if (kspl > 1)       atomicAdd(&((float*)Cv)[(size_t)row * N + col], v);
                else if (c_is_f32)  ((float*)Cv)[(size_t)row * N + col] = v;
                else                ((u16*)Cv)[(size_t)row * N + col] = f2b(v);
            }
}

// ---------------- Flash attention, GQA, causal, fused paired q-tiles ---------
// (unchanged from round 6's verified version: V LDS-staged dbuf + XOR swizzle)
__global__ __launch_bounds__(512) void attn_kernel(
    const u16* __restrict__ QKV, const u16* __restrict__ VT, u16* __restrict__ O) {
    const int S = 2048, RS = 3072, DO = 2048;
    const int bid = blockIdx.x;                 // 0..511
    const int swz = (bid & 7) * 64 + (bid >> 3);
    const int p = swz & 15, hp = (swz >> 4) & 15, b = swz >> 8;
    const int g = hp >> 1;
    const int qtl = p, qth = 31 - p;            // qtl <= 15 < 16 <= qth
    const int tid = threadIdx.x;
    const int lane = tid & 63, wave = tid >> 6; // wave 0..7
    const int hw = wave >> 2, lw = wave & 3;    // head-half, local wave
    const int h = hp * 2 + hw;
    const int ln = lane & 15, quad = lane >> 4;

    __shared__ u16 Ks[2][64 * 64];              // swizzled, stride 64
    __shared__ u16 Vs[2][64 * 64];              // swizzled, stride 64
    __shared__ u16 Ps[4][64 * 68];
    u16* Psh = &Ps[hw * 2 + 0][0];
    u16* Psl = &Ps[hw * 2 + 1][0];

    const u16* Qb = QKV + (size_t)b * S * RS + h * 64 + quad * 8;
    bf16x8 aqh0 = *(const bf16x8*)(Qb + (size_t)(qth * 64 + lw * 16 + ln) * RS);
    bf16x8 aqh1 = *(const bf16x8*)(Qb + (size_t)(qth * 64 + lw * 16 + ln) * RS + 32);
    bf16x8 aql0 = *(const bf16x8*)(Qb + (size_t)(qtl * 64 + lw * 16 + ln) * RS);
    bf16x8 aql1 = *(const bf16x8*)(Qb + (size_t)(qtl * 64 + lw * 16 + ln) * RS + 32);

    const u16* Kb = QKV + (size_t)b * S * RS + 2048 + g * 64;
    const u16* VTb = VT + (size_t)(b * 8 + g) * 64 * S;

    const bf16x8 vones = {0x3F80, 0x3F80, 0x3F80, 0x3F80, 0x3F80, 0x3F80, 0x3F80, 0x3F80};

    f32x4 acch[5] = {}, accl[5] = {};  // [0..3]=O tiles, [4]=row-sum l

    const int kr = tid >> 3;            // 0..63 (row; K: k-row, V: d-row)
    const int ks = tid & 7;             // 16B slot in row
    const int kswz = ((ks ^ (kr & 7)) * 8);
    bf16x8 kreg, vreg;
    auto loadKV = [&](int kt) {
        kreg = *(const bf16x8*)(Kb + (size_t)(kt * 64 + kr) * RS + ks * 8);
        vreg = *(const bf16x8*)(VTb + (size_t)kr * S + kt * 64 + ks * 8);
    };

    auto body = [&](int kt, bool DUAL, bool MH, bool ML) {
        u16* KsC = &Ks[kt & 1][0];
        u16* VsC = &Vs[kt & 1][0];
        if (kt < qth) {   // stage NEXT tile; readers finished last body
            u16* KsN = &Ks[(kt & 1) ^ 1][0];
            u16* VsN = &Vs[(kt & 1) ^ 1][0];
            *(bf16x8*)&KsN[kr * 64 + kswz] = kreg;
            *(bf16x8*)&VsN[kr * 64 + kswz] = vreg;
        }
        if (kt + 2 <= qth) loadKV(kt + 2);

        const int rsw = ln & 7;
        f32x4 sh[4] = {}, sl[4] = {};
        __builtin_amdgcn_s_setprio(1);
        #pragma unroll
        for (int nt = 0; nt < 4; nt++) {
            bf16x8 bk0 = *(const bf16x8*)&KsC[(nt * 16 + ln) * 64 + ((quad ^ rsw) * 8)];
            bf16x8 bk1 = *(const bf16x8*)&KsC[(nt * 16 + ln) * 64 + (((quad + 4) ^ rsw) * 8)];
            sh[nt] = __builtin_amdgcn_mfma_f32_16x16x32_bf16(aqh0, bk0, sh[nt], 0, 0, 0);
            sh[nt] = __builtin_amdgcn_mfma_f32_16x16x32_bf16(aqh1, bk1, sh[nt], 0, 0, 0);
            if (DUAL) {
                sl[nt] = __builtin_amdgcn_mfma_f32_16x16x32_bf16(aql0, bk0, sl[nt], 0, 0, 0);
                sl[nt] = __builtin_amdgcn_mfma_f32_16x16x32_bf16(aql1, bk1, sl[nt], 0, 0, 0);
            }
        }
        __builtin_amdgcn_s_setprio(0);

        if (MH) {
            #pragma unroll
            for (int nt = 0; nt < 4; nt++)
                #pragma unroll
                for (int r = 0; r < 4; r++)
                    if (nt * 16 + ln > lw * 16 + quad * 4 + r) sh[nt][r] = -INFINITY;
        }
        #pragma unroll
        for (int nt = 0; nt < 4; nt++)
            #pragma unroll
            for (int r = 0; r < 4; r++) {
                float pv = exp2f(sh[nt][r]);
                Psh[(lw * 16 + quad * 4 + r) * 68 + nt * 16 + ln] =
                    (u16)(__builtin_bit_cast(unsigned int, pv) >> 16);
            }
        if (DUAL) {
            if (ML) {
                #pragma unroll
                for (int nt = 0; nt < 4; nt++)
                    #pragma unroll
                    for (int r = 0; r < 4; r++)
                        if (nt * 16 + ln > lw * 16 + quad * 4 + r) sl[nt][r] = -INFINITY;
            }
            #pragma unroll
            for (int nt = 0; nt < 4; nt++)
                #pragma unroll
                for (int r = 0; r < 4; r++) {
                    float pv = exp2f(sl[nt][r]);
                    Psl[(lw * 16 + quad * 4 + r) * 68 + nt * 16 + ln] =
                        (u16)(__builtin_bit_cast(unsigned int, pv) >> 16);
                }
        }
        // no barrier: Ps rows are wave-private (same-wave LDS ordering)

        __builtin_amdgcn_s_setprio(1);
        #pragma unroll
        for (int kk = 0; kk < 2; kk++) {
            bf16x8 aph = *(const bf16x8*)&Psh[(lw * 16 + ln) * 68 + kk * 32 + quad * 8];
            bf16x8 apl;
            if (DUAL) apl = *(const bf16x8*)&Psl[(lw * 16 + ln) * 68 + kk * 32 + quad * 8];
            #pragma unroll
            for (int nt = 0; nt < 4; nt++) {
                bf16x8 bv = *(const bf16x8*)&VsC[(nt * 16 + ln) * 64
                                                 + (((kk * 4 + quad) ^ rsw) * 8)];
                acch[nt] = __builtin_amdgcn_mfma_f32_16x16x32_bf16(aph, bv, acch[nt], 0, 0, 0);
                if (DUAL)
                    accl[nt] = __builtin_amdgcn_mfma_f32_16x16x32_bf16(apl, bv, accl[nt], 0, 0, 0);
            }
            acch[4] = __builtin_amdgcn_mfma_f32_16x16x32_bf16(aph, vones, acch[4], 0, 0, 0);
            if (DUAL)
                accl[4] = __builtin_amdgcn_mfma_f32_16x16x32_bf16(apl, vones, accl[4], 0, 0, 0);
        }
        __builtin_amdgcn_s_setprio(0);

        __syncthreads();               // single barrier per body
    };

    loadKV(0);
    *(bf16x8*)&Ks[0][kr * 64 + kswz] = kreg;
    *(bf16x8*)&Vs[0][kr * 64 + kswz] = vreg;
    loadKV(1);
    __syncthreads();

    for (int kt = 0; kt < qtl; kt++) body(kt, true, false, false);
    body(qtl, true, false, true);
    for (int kt = qtl + 1; kt < qth; kt++) body(kt, false, false, false);
    body(qth, false, true, false);

    u16* Ob = O + (size_t)b * S * DO + h * 64;
    #pragma unroll
    for (int r = 0; r < 4; r++) {
        float invh = 1.0f / acch[4][r];
        float invl = 1.0f / accl[4][r];
        int qh = qth * 64 + lw * 16 + quad * 4 + r;
        int ql = qtl * 64 + lw * 16 + quad * 4 + r;
        #pragma unroll
        for (int nt = 0; nt < 4; nt++) {
            Ob[(size_t)qh * DO + nt * 16 + ln] = f2b(acch[nt][r] * invh);
            Ob[(size_t)ql * DO + nt * 16 + ln] = f2b(accl[nt][r] * invl);
        }
    }
}

extern "C" void kernel_launch(void* const* d_in, const int* in_sizes, int n_in,
                              void* d_out, int out_size, void* d_ws, size_t ws_size,
                              hipStream_t stream) {
    const float* x  = (const float*)d_in[0];
    const float* wq = (const float*)d_in[1];
    const float* wk = (const float*)d_in[2];
    const float* wv = (const float*)d_in[3];
    const float* wo = (const float*)d_in[4];

    const int B = 2, S = 2048, D = 2048;
    const int M = B * S;         // 4096
    const int NQKV = 3072;

    char* ws = (char*)d_ws;
    size_t off = 0;
    auto alloc = [&](size_t bytes) {
        void* p = ws + off;
        off += (bytes + 255) & ~(size_t)255;
        return p;
    };
    u16* xb    = (u16*)alloc((size_t)M * D * 2);        // 16 MB; reused as AO
    u16* wqkvb = (u16*)alloc((size_t)NQKV * D * 2);     // 12 MB; reused as VT
    u16* wob   = (u16*)alloc((size_t)D * D * 2);        // 8 MB
    u16* QKV   = (u16*)alloc((size_t)M * NQKV * 2);     // 24 MB
    u16* AO = xb;      // xb dead after QKV GEMM
    u16* VT = wqkvb;   // wqkvb dead after QKV GEMM

    cast_all<<<dim3(9216), 256, 0, stream>>>(x, wq, wk, wv, wo, xb, wqkvb, wob);

    gemm_bt256<<<dim3(NQKV / 256, M / 256, 1), 512, 0, stream>>>(
        xb, wqkvb, QKV, M, NQKV, D, 0, 1);

    const float sscale = 0.125f * LOG2E;
    rope_vtrans<<<dim3(5632), 256, 0, stream>>>(QKV, VT, sscale);

    attn_kernel<<<dim3(512), 512, 0, stream>>>(QKV, VT, AO);

    // GEMM2: split-K=2 -> 256 blocks (full machine, was 128 = half idle).
    // d_out is memset to 0 by the harness before every launch; partials
    // accumulate via f32 atomicAdd.
    gemm_bt256<<<dim3(D / 256, M / 256, 2), 512, 0, stream>>>(
        AO, wob, d_out, M, D, D, 1, 2);
}

// Round 8
// 323.024 us; speedup vs baseline: 1.1091x; 1.1091x over previous
//
#include <hip/hip_runtime.h>

typedef unsigned short u16;
typedef __attribute__((ext_vector_type(8))) short bf16x8;
typedef __attribute__((ext_vector_type(4))) float f32x4;

#define LOG2E 1.44269504088896340736f

__device__ inline u16 f2b(float f) {
    unsigned int u = __builtin_bit_cast(unsigned int, f);
    unsigned int r = u + 0x7fffu + ((u >> 16) & 1u);
    return (u16)(r >> 16);
}
__device__ inline float b2f(u16 h) {
    unsigned int u = ((unsigned int)h) << 16;
    return __builtin_bit_cast(float, u);
}

#define GLOAD_LDS16(g, l) \
    __builtin_amdgcn_global_load_lds( \
        (const __attribute__((address_space(1))) unsigned int*)(g), \
        (__attribute__((address_space(3))) unsigned int*)(l), 16, 0, 0)

// ---------------- fused cast fp32 -> bf16 for all 5 inputs, 8 elems/thread ----
__global__ __launch_bounds__(256) void cast_all(
    const float* __restrict__ x, const float* __restrict__ wq,
    const float* __restrict__ wk, const float* __restrict__ wv,
    const float* __restrict__ wo, u16* __restrict__ xb,
    u16* __restrict__ wqkvb, u16* __restrict__ wob) {
    long i = ((long)blockIdx.x * 256 + threadIdx.x) * 8;
    const float* s;
    u16* d;
    if (i < 8388608)       { s = x  + i;              d = xb + i; }
    else if (i < 12582912) { s = wq + (i - 8388608);  d = wqkvb + (i - 8388608); }
    else if (i < 13631488) { s = wk + (i - 12582912); d = wqkvb + 4194304 + (i - 12582912); }
    else if (i < 14680064) { s = wv + (i - 13631488); d = wqkvb + 5242880 + (i - 13631488); }
    else                   { s = wo + (i - 14680064); d = wob + (i - 14680064); }
    float4 v0 = *(const float4*)s;
    float4 v1 = *(const float4*)(s + 4);
    ushort4 o0 = make_ushort4(f2b(v0.x), f2b(v0.y), f2b(v0.z), f2b(v0.w));
    ushort4 o1 = make_ushort4(f2b(v1.x), f2b(v1.y), f2b(v1.z), f2b(v1.w));
    *(ushort4*)d = o0;
    *(ushort4*)(d + 4) = o1;
}

// ---------------- fused RoPE (Q+K) and V-transpose in one launch ----------------
__global__ __launch_bounds__(256) void rope_vtrans(
    u16* __restrict__ qkv, u16* __restrict__ VT, float qscale) {
    const int S = 2048, RS = 3072;
    int tid = threadIdx.x;
    if (blockIdx.x < 5120) {
        int idx = blockIdx.x * 256 + tid;   // < 4096*320
        int row = idx / 320;
        int rem = idx - row * 320;
        int head = rem >> 3, chunk = rem & 7;
        int pos = row & 2047;
        int coloff;
        float scale;
        if (head < 32) { coloff = head * 64;               scale = qscale; }
        else           { coloff = 2048 + (head - 32) * 64; scale = 1.0f; }
        u16* p = qkv + (size_t)row * RS + coloff + chunk * 8;
        bf16x8 v = *(bf16x8*)p;
        float t0 = exp2f((float)(chunk * 4) * -0.41524101186092f);
        const float tc[4] = {1.0f, 0.74989420933246f, 0.56234132519035f, 0.42169650342858f};
        float fpos = (float)pos;
        #pragma unroll
        for (int i = 0; i < 4; i++) {
            float f = fpos * (t0 * tc[i]);
            float rev = f * 0.15915494309189535f;  // radians -> revolutions
            rev = rev - floorf(rev);
            float sn = __builtin_amdgcn_sinf(rev);
            float cs = __builtin_amdgcn_cosf(rev);
            float e0 = b2f((u16)v[2 * i]), e1 = b2f((u16)v[2 * i + 1]);
            v[2 * i]     = (short)f2b((e0 * cs - e1 * sn) * scale);
            v[2 * i + 1] = (short)f2b((e1 * cs + e0 * sn) * scale);
        }
        *(bf16x8*)p = v;
    } else {
        int bid = blockIdx.x - 5120;        // 0..511
        int st = bid & 31, g = (bid >> 5) & 7, b = bid >> 8;
        __shared__ u16 T[64 * 72];
        for (int c = tid; c < 512; c += 256) {
            int sr = c >> 3, dc = (c & 7) * 8;
            *(bf16x8*)&T[sr * 72 + dc] =
                *(const bf16x8*)(qkv + ((size_t)b * S + st * 64 + sr) * RS + 2560 + g * 64 + dc);
        }
        __syncthreads();
        for (int c = tid; c < 512; c += 256) {
            int d = c >> 3, sc = (c & 7) * 8;
            bf16x8 o;
            #pragma unroll
            for (int j = 0; j < 8; j++) o[j] = (short)T[(sc + j) * 72 + d];
            *(bf16x8*)(VT + ((size_t)((b * 8 + g) * 64 + d)) * S + st * 64 + sc) = o;
        }
    }
}

#define BAR()    do { __builtin_amdgcn_s_barrier(); \
                      __builtin_amdgcn_sched_barrier(0); } while (0)
#define LGKM0()  do { asm volatile("s_waitcnt lgkmcnt(0)" ::: "memory"); \
                      __builtin_amdgcn_sched_barrier(0); } while (0)
#define VMCNT(n) do { asm volatile("s_waitcnt vmcnt(" #n ")" ::: "memory"); \
                      __builtin_amdgcn_sched_barrier(0); } while (0)

// ---------------- GEMM 256x256 8-phase: C[M,N]=A[M,K]*B[N,K]^T --------------
// (round-6 verified version, kspl reverted — used for GEMM1, grid 12x16=192)
#define MMAQ(MH, NH, AR, BR) do { \
    __builtin_amdgcn_s_setprio(1); \
    _Pragma("unroll") \
    for (int m2 = 0; m2 < 4; m2++) { \
        _Pragma("unroll") \
        for (int n2 = 0; n2 < 2; n2++) { \
            acc[(MH)*4+m2][(NH)*2+n2] = __builtin_amdgcn_mfma_f32_16x16x32_bf16( \
                AR[m2][0], BR[n2][0], acc[(MH)*4+m2][(NH)*2+n2], 0, 0, 0); \
            acc[(MH)*4+m2][(NH)*2+n2] = __builtin_amdgcn_mfma_f32_16x16x32_bf16( \
                AR[m2][1], BR[n2][1], acc[(MH)*4+m2][(NH)*2+n2], 0, 0, 0); \
        } \
    } \
    __builtin_amdgcn_s_setprio(0); \
} while (0)

__global__ __launch_bounds__(512) void gemm_bt256(
    const u16* __restrict__ A, const u16* __restrict__ B, void* __restrict__ Cv,
    int M, int N, int K, int c_is_f32) {
    __shared__ u16 As[32768];   // [dbuf*2+half][128*64]
    __shared__ u16 Bs[32768];
    const int tid = threadIdx.x;
    const int w = tid >> 6, lane = tid & 63;
    const int ln = lane & 15, quad = lane >> 4;
    const int wr = w >> 2, wc = w & 3;

    const int gx = gridDim.x;
    const int nwg = gx * gridDim.y;
    const int bid = blockIdx.y * gx + blockIdx.x;
    const int cpx = nwg >> 3;
    const int swz = (bid & 7) * cpx + (bid >> 3);
    const int m0 = (swz / gx) * 256, n0 = (swz % gx) * 256;

    const int l3 = lane >> 3, l7 = lane & 7;
    const u16* Ast = A + (size_t)(m0 + w * 8 + l3) * K + (l7 ^ l3) * 8;
    const u16* Bst = B + (size_t)(n0 + w * 8 + l3) * K + (l7 ^ l3) * 8;

    auto stageA = [&](int u, int h) {
        const u16* g = Ast + (size_t)(h * 128) * K + u * 64;
        u16* d = As + ((u & 1) * 2 + h) * 8192 + w * 512;
        GLOAD_LDS16(g, d);
        GLOAD_LDS16(g + (size_t)64 * K, d + 4096);
    };
    auto stageB = [&](int u, int h) {
        const u16* g = Bst + (size_t)(h * 128) * K + u * 64;
        u16* d = Bs + ((u & 1) * 2 + h) * 8192 + w * 512;
        GLOAD_LDS16(g, d);
        GLOAD_LDS16(g + (size_t)64 * K, d + 4096);
    };

    const int xs0 = ((quad) ^ (ln & 7)) * 8;
    const int xs1 = ((4 + quad) ^ (ln & 7)) * 8;

    bf16x8 a[4][2], b0[2][2], b1[2][2];
    auto loadA = [&](int u, int mh, bf16x8 (&dst)[4][2]) {
        const u16* base = As + ((u & 1) * 2 + wr) * 8192 + (mh * 64 + ln) * 64;
        #pragma unroll
        for (int m2 = 0; m2 < 4; m2++) {
            dst[m2][0] = *(const bf16x8*)(base + m2 * 1024 + xs0);
            dst[m2][1] = *(const bf16x8*)(base + m2 * 1024 + xs1);
        }
    };
    auto loadB = [&](int u, int nh, bf16x8 (&dst)[2][2]) {
        const u16* base = Bs + ((u & 1) * 2 + (wc >> 1)) * 8192
                        + ((wc & 1) * 64 + nh * 32 + ln) * 64;
        #pragma unroll
        for (int n2 = 0; n2 < 2; n2++) {
            dst[n2][0] = *(const bf16x8*)(base + n2 * 1024 + xs0);
            dst[n2][1] = *(const bf16x8*)(base + n2 * 1024 + xs1);
        }
    };

    f32x4 acc[8][4] = {};
    const int NT = K >> 6;

    stageB(0, 0); stageB(0, 1);
    stageA(0, 0); stageA(0, 1);
    stageB(1, 0); stageB(1, 1);
    VMCNT(4);
    BAR();

    for (int u = 0; u < NT; ++u) {
        loadA(u, 0, a);
        loadB(u, 0, b0);
        if (u + 1 < NT) stageA(u + 1, 0);
        BAR(); LGKM0();
        MMAQ(0, 0, a, b0);
        BAR();
        loadB(u, 1, b1);
        if (u + 1 < NT) stageA(u + 1, 1);
        BAR(); LGKM0();
        MMAQ(0, 1, a, b1);
        BAR();
        loadA(u, 1, a);
        if (u + 2 < NT) stageB(u + 2, 0);
        BAR(); LGKM0();
        MMAQ(1, 1, a, b1);
        BAR();
        if (u + 2 < NT) stageB(u + 2, 1);
        BAR();
        MMAQ(1, 0, a, b0);
        if (u + 2 < NT)      { VMCNT(4); }
        else if (u + 1 < NT) { VMCNT(0); }
        BAR();
    }

    #pragma unroll
    for (int mi = 0; mi < 8; mi++)
        #pragma unroll
        for (int ni = 0; ni < 4; ni++)
            #pragma unroll
            for (int r = 0; r < 4; r++) {
                int row = m0 + wr * 128 + mi * 16 + quad * 4 + r;
                int col = n0 + wc * 64 + ni * 16 + ln;
                float v = acc[mi][ni][r];
                if (c_is_f32) ((float*)Cv)[(size_t)row * N + col] = v;
                else          ((u16*)Cv)[(size_t)row * N + col] = f2b(v);
            }
}

// ---------------- GEMM 256x128 8-phase: C[M,N]=A[M,K]*B[N,K]^T --------------
// ROUND-7: full-occupancy variant for GEMM2. Grid (2048/128)x(4096/256) =
// 16x16 = 256 blocks = exactly 1/CU (was 128 = half machine idle; split-K
// atomics cost MORE than the idle half — round-7 lesson). Same debugged
// 4-phase skeleton; B halves are 64 rows -> stageB = 1 gload. Ledger:
// prologue {B0:2,A0:4,B1:2} -> vmcnt(2); P4 tail outstanding {B(u+1):2,
// A(u+1):4,B(u+2):2} -> vmcnt(2) (B(u+2) stays in flight); u=NT-2 -> vmcnt(0).
// Swizzle invariants identical (stage rows ≡ l3, read rows ≡ ln mod 8).
#define MMAQ2(MH, NH, AR, BR) do { \
    __builtin_amdgcn_s_setprio(1); \
    _Pragma("unroll") \
    for (int m2 = 0; m2 < 4; m2++) { \
        acc[(MH)*4+m2][(NH)] = __builtin_amdgcn_mfma_f32_16x16x32_bf16( \
            AR[m2][0], BR[0], acc[(MH)*4+m2][(NH)], 0, 0, 0); \
        acc[(MH)*4+m2][(NH)] = __builtin_amdgcn_mfma_f32_16x16x32_bf16( \
            AR[m2][1], BR[1], acc[(MH)*4+m2][(NH)], 0, 0, 0); \
    } \
    __builtin_amdgcn_s_setprio(0); \
} while (0)

__global__ __launch_bounds__(512) void gemm_bt256x128(
    const u16* __restrict__ A, const u16* __restrict__ B, void* __restrict__ Cv,
    int M, int N, int K, int c_is_f32) {
    __shared__ u16 As[32768];   // [dbuf*2+half][128*64] (halves = 128 rows)
    __shared__ u16 Bs[16384];   // [dbuf*2+half][64*64]  (halves = 64 rows)
    const int tid = threadIdx.x;
    const int w = tid >> 6, lane = tid & 63;
    const int ln = lane & 15, quad = lane >> 4;
    const int wr = w >> 2, wc = w & 3;   // wave: 2M x 4N, per-wave out 128x32

    const int gx = gridDim.x;            // N/128
    const int nwg = gx * gridDim.y;
    const int bid = blockIdx.y * gx + blockIdx.x;
    const int cpx = nwg >> 3;
    const int swz = (bid & 7) * cpx + (bid >> 3);
    const int m0 = (swz / gx) * 256, n0 = (swz % gx) * 128;

    const int l3 = lane >> 3, l7 = lane & 7;
    const u16* Ast = A + (size_t)(m0 + w * 8 + l3) * K + (l7 ^ l3) * 8;
    const u16* Bst = B + (size_t)(n0 + w * 8 + l3) * K + (l7 ^ l3) * 8;

    auto stageA = [&](int u, int h) {     // 2 gloads (128-row half)
        const u16* g = Ast + (size_t)(h * 128) * K + u * 64;
        u16* d = As + ((u & 1) * 2 + h) * 8192 + w * 512;
        GLOAD_LDS16(g, d);
        GLOAD_LDS16(g + (size_t)64 * K, d + 4096);
    };
    auto stageB = [&](int u, int h) {     // 1 gload (64-row half)
        const u16* g = Bst + (size_t)(h * 64) * K + u * 64;
        u16* d = Bs + ((u & 1) * 2 + h) * 4096 + w * 512;
        GLOAD_LDS16(g, d);
    };

    const int xs0 = ((quad) ^ (ln & 7)) * 8;
    const int xs1 = ((4 + quad) ^ (ln & 7)) * 8;

    bf16x8 a[4][2], b0[2], b1[2];
    auto loadA = [&](int u, int mh, bf16x8 (&dst)[4][2]) {
        const u16* base = As + ((u & 1) * 2 + wr) * 8192 + (mh * 64 + ln) * 64;
        #pragma unroll
        for (int m2 = 0; m2 < 4; m2++) {
            dst[m2][0] = *(const bf16x8*)(base + m2 * 1024 + xs0);
            dst[m2][1] = *(const bf16x8*)(base + m2 * 1024 + xs1);
        }
    };
    // wave's B rows: wc*32 + nh*16 + ln; half = wc>>1, in-half = (wc&1)*32+nh*16+ln
    auto loadB = [&](int u, int nh, bf16x8 (&dst)[2]) {
        const u16* base = Bs + ((u & 1) * 2 + (wc >> 1)) * 4096
                        + ((wc & 1) * 32 + nh * 16 + ln) * 64;
        dst[0] = *(const bf16x8*)(base + xs0);
        dst[1] = *(const bf16x8*)(base + xs1);
    };

    f32x4 acc[8][2] = {};
    const int NT = K >> 6;

    stageB(0, 0); stageB(0, 1);      // 2 loads
    stageA(0, 0); stageA(0, 1);      // 4 loads
    stageB(1, 0); stageB(1, 1);      // 2 loads
    VMCNT(2);
    BAR();

    for (int u = 0; u < NT; ++u) {
        loadA(u, 0, a);
        loadB(u, 0, b0);
        if (u + 1 < NT) stageA(u + 1, 0);
        BAR(); LGKM0();
        MMAQ2(0, 0, a, b0);
        BAR();
        loadB(u, 1, b1);
        if (u + 1 < NT) stageA(u + 1, 1);
        BAR(); LGKM0();
        MMAQ2(0, 1, a, b1);
        BAR();
        loadA(u, 1, a);
        if (u + 2 < NT) stageB(u + 2, 0);
        BAR(); LGKM0();
        MMAQ2(1, 1, a, b1);
        BAR();
        if (u + 2 < NT) stageB(u + 2, 1);
        BAR();
        MMAQ2(1, 0, a, b0);
        if (u + 2 < NT)      { VMCNT(2); }
        else if (u + 1 < NT) { VMCNT(0); }
        BAR();
    }

    #pragma unroll
    for (int mi = 0; mi < 8; mi++)
        #pragma unroll
        for (int ni = 0; ni < 2; ni++)
            #pragma unroll
            for (int r = 0; r < 4; r++) {
                int row = m0 + wr * 128 + mi * 16 + quad * 4 + r;
                int col = n0 + wc * 32 + ni * 16 + ln;
                float v = acc[mi][ni][r];
                if (c_is_f32) ((float*)Cv)[(size_t)row * N + col] = v;
                else          ((u16*)Cv)[(size_t)row * N + col] = f2b(v);
            }
}

// ---------------- Flash attention, GQA, causal, fused paired q-tiles ---------
// (unchanged from round 6's verified version: V LDS-staged dbuf + XOR swizzle)
__global__ __launch_bounds__(512) void attn_kernel(
    const u16* __restrict__ QKV, const u16* __restrict__ VT, u16* __restrict__ O) {
    const int S = 2048, RS = 3072, DO = 2048;
    const int bid = blockIdx.x;                 // 0..511
    const int swz = (bid & 7) * 64 + (bid >> 3);
    const int p = swz & 15, hp = (swz >> 4) & 15, b = swz >> 8;
    const int g = hp >> 1;
    const int qtl = p, qth = 31 - p;            // qtl <= 15 < 16 <= qth
    const int tid = threadIdx.x;
    const int lane = tid & 63, wave = tid >> 6; // wave 0..7
    const int hw = wave >> 2, lw = wave & 3;    // head-half, local wave
    const int h = hp * 2 + hw;
    const int ln = lane & 15, quad = lane >> 4;

    __shared__ u16 Ks[2][64 * 64];              // swizzled, stride 64
    __shared__ u16 Vs[2][64 * 64];              // swizzled, stride 64
    __shared__ u16 Ps[4][64 * 68];
    u16* Psh = &Ps[hw * 2 + 0][0];
    u16* Psl = &Ps[hw * 2 + 1][0];

    const u16* Qb = QKV + (size_t)b * S * RS + h * 64 + quad * 8;
    bf16x8 aqh0 = *(const bf16x8*)(Qb + (size_t)(qth * 64 + lw * 16 + ln) * RS);
    bf16x8 aqh1 = *(const bf16x8*)(Qb + (size_t)(qth * 64 + lw * 16 + ln) * RS + 32);
    bf16x8 aql0 = *(const bf16x8*)(Qb + (size_t)(qtl * 64 + lw * 16 + ln) * RS);
    bf16x8 aql1 = *(const bf16x8*)(Qb + (size_t)(qtl * 64 + lw * 16 + ln) * RS + 32);

    const u16* Kb = QKV + (size_t)b * S * RS + 2048 + g * 64;
    const u16* VTb = VT + (size_t)(b * 8 + g) * 64 * S;

    const bf16x8 vones = {0x3F80, 0x3F80, 0x3F80, 0x3F80, 0x3F80, 0x3F80, 0x3F80, 0x3F80};

    f32x4 acch[5] = {}, accl[5] = {};  // [0..3]=O tiles, [4]=row-sum l

    const int kr = tid >> 3;            // 0..63 (row; K: k-row, V: d-row)
    const int ks = tid & 7;             // 16B slot in row
    const int kswz = ((ks ^ (kr & 7)) * 8);
    bf16x8 kreg, vreg;
    auto loadKV = [&](int kt) {
        kreg = *(const bf16x8*)(Kb + (size_t)(kt * 64 + kr) * RS + ks * 8);
        vreg = *(const bf16x8*)(VTb + (size_t)kr * S + kt * 64 + ks * 8);
    };

    auto body = [&](int kt, bool DUAL, bool MH, bool ML) {
        u16* KsC = &Ks[kt & 1][0];
        u16* VsC = &Vs[kt & 1][0];
        if (kt < qth) {   // stage NEXT tile; readers finished last body
            u16* KsN = &Ks[(kt & 1) ^ 1][0];
            u16* VsN = &Vs[(kt & 1) ^ 1][0];
            *(bf16x8*)&KsN[kr * 64 + kswz] = kreg;
            *(bf16x8*)&VsN[kr * 64 + kswz] = vreg;
        }
        if (kt + 2 <= qth) loadKV(kt + 2);

        const int rsw = ln & 7;
        f32x4 sh[4] = {}, sl[4] = {};
        __builtin_amdgcn_s_setprio(1);
        #pragma unroll
        for (int nt = 0; nt < 4; nt++) {
            bf16x8 bk0 = *(const bf16x8*)&KsC[(nt * 16 + ln) * 64 + ((quad ^ rsw) * 8)];
            bf16x8 bk1 = *(const bf16x8*)&KsC[(nt * 16 + ln) * 64 + (((quad + 4) ^ rsw) * 8)];
            sh[nt] = __builtin_amdgcn_mfma_f32_16x16x32_bf16(aqh0, bk0, sh[nt], 0, 0, 0);
            sh[nt] = __builtin_amdgcn_mfma_f32_16x16x32_bf16(aqh1, bk1, sh[nt], 0, 0, 0);
            if (DUAL) {
                sl[nt] = __builtin_amdgcn_mfma_f32_16x16x32_bf16(aql0, bk0, sl[nt], 0, 0, 0);
                sl[nt] = __builtin_amdgcn_mfma_f32_16x16x32_bf16(aql1, bk1, sl[nt], 0, 0, 0);
            }
        }
        __builtin_amdgcn_s_setprio(0);

        if (MH) {
            #pragma unroll
            for (int nt = 0; nt < 4; nt++)
                #pragma unroll
                for (int r = 0; r < 4; r++)
                    if (nt * 16 + ln > lw * 16 + quad * 4 + r) sh[nt][r] = -INFINITY;
        }
        #pragma unroll
        for (int nt = 0; nt < 4; nt++)
            #pragma unroll
            for (int r = 0; r < 4; r++) {
                float pv = exp2f(sh[nt][r]);
                Psh[(lw * 16 + quad * 4 + r) * 68 + nt * 16 + ln] =
                    (u16)(__builtin_bit_cast(unsigned int, pv) >> 16);
            }
        if (DUAL) {
            if (ML) {
                #pragma unroll
                for (int nt = 0; nt < 4; nt++)
                    #pragma unroll
                    for (int r = 0; r < 4; r++)
                        if (nt * 16 + ln > lw * 16 + quad * 4 + r) sl[nt][r] = -INFINITY;
            }
            #pragma unroll
            for (int nt = 0; nt < 4; nt++)
                #pragma unroll
                for (int r = 0; r < 4; r++) {
                    float pv = exp2f(sl[nt][r]);
                    Psl[(lw * 16 + quad * 4 + r) * 68 + nt * 16 + ln] =
                        (u16)(__builtin_bit_cast(unsigned int, pv) >> 16);
                }
        }
        // no barrier: Ps rows are wave-private (same-wave LDS ordering)

        __builtin_amdgcn_s_setprio(1);
        #pragma unroll
        for (int kk = 0; kk < 2; kk++) {
            bf16x8 aph = *(const bf16x8*)&Psh[(lw * 16 + ln) * 68 + kk * 32 + quad * 8];
            bf16x8 apl;
            if (DUAL) apl = *(const bf16x8*)&Psl[(lw * 16 + ln) * 68 + kk * 32 + quad * 8];
            #pragma unroll
            for (int nt = 0; nt < 4; nt++) {
                bf16x8 bv = *(const bf16x8*)&VsC[(nt * 16 + ln) * 64
                                                 + (((kk * 4 + quad) ^ rsw) * 8)];
                acch[nt] = __builtin_amdgcn_mfma_f32_16x16x32_bf16(aph, bv, acch[nt], 0, 0, 0);
                if (DUAL)
                    accl[nt] = __builtin_amdgcn_mfma_f32_16x16x32_bf16(apl, bv, accl[nt], 0, 0, 0);
            }
            acch[4] = __builtin_amdgcn_mfma_f32_16x16x32_bf16(aph, vones, acch[4], 0, 0, 0);
            if (DUAL)
                accl[4] = __builtin_amdgcn_mfma_f32_16x16x32_bf16(apl, vones, accl[4], 0, 0, 0);
        }
        __builtin_amdgcn_s_setprio(0);

        __syncthreads();               // single barrier per body
    };

    loadKV(0);
    *(bf16x8*)&Ks[0][kr * 64 + kswz] = kreg;
    *(bf16x8*)&Vs[0][kr * 64 + kswz] = vreg;
    loadKV(1);
    __syncthreads();

    for (int kt = 0; kt < qtl; kt++) body(kt, true, false, false);
    body(qtl, true, false, true);
    for (int kt = qtl + 1; kt < qth; kt++) body(kt, false, false, false);
    body(qth, false, true, false);

    u16* Ob = O + (size_t)b * S * DO + h * 64;
    #pragma unroll
    for (int r = 0; r < 4; r++) {
        float invh = 1.0f / acch[4][r];
        float invl = 1.0f / accl[4][r];
        int qh = qth * 64 + lw * 16 + quad * 4 + r;
        int ql = qtl * 64 + lw * 16 + quad * 4 + r;
        #pragma unroll
        for (int nt = 0; nt < 4; nt++) {
            Ob[(size_t)qh * DO + nt * 16 + ln] = f2b(acch[nt][r] * invh);
            Ob[(size_t)ql * DO + nt * 16 + ln] = f2b(accl[nt][r] * invl);
        }
    }
}

extern "C" void kernel_launch(void* const* d_in, const int* in_sizes, int n_in,
                              void* d_out, int out_size, void* d_ws, size_t ws_size,
                              hipStream_t stream) {
    const float* x  = (const float*)d_in[0];
    const float* wq = (const float*)d_in[1];
    const float* wk = (const float*)d_in[2];
    const float* wv = (const float*)d_in[3];
    const float* wo = (const float*)d_in[4];

    const int B = 2, S = 2048, D = 2048;
    const int M = B * S;         // 4096
    const int NQKV = 3072;

    char* ws = (char*)d_ws;
    size_t off = 0;
    auto alloc = [&](size_t bytes) {
        void* p = ws + off;
        off += (bytes + 255) & ~(size_t)255;
        return p;
    };
    u16* xb    = (u16*)alloc((size_t)M * D * 2);        // 16 MB; reused as AO
    u16* wqkvb = (u16*)alloc((size_t)NQKV * D * 2);     // 12 MB; reused as VT
    u16* wob   = (u16*)alloc((size_t)D * D * 2);        // 8 MB
    u16* QKV   = (u16*)alloc((size_t)M * NQKV * 2);     // 24 MB
    u16* AO = xb;      // xb dead after QKV GEMM
    u16* VT = wqkvb;   // wqkvb dead after QKV GEMM

    cast_all<<<dim3(9216), 256, 0, stream>>>(x, wq, wk, wv, wo, xb, wqkvb, wob);

    gemm_bt256<<<dim3(NQKV / 256, M / 256), 512, 0, stream>>>(
        xb, wqkvb, QKV, M, NQKV, D, 0);

    const float sscale = 0.125f * LOG2E;
    rope_vtrans<<<dim3(5632), 256, 0, stream>>>(QKV, VT, sscale);

    attn_kernel<<<dim3(512), 512, 0, stream>>>(QKV, VT, AO);

    // GEMM2: 256x128 tile -> 16x16 = 256 blocks = full machine, plain stores.
    gemm_bt256x128<<<dim3(D / 128, M / 256), 512, 0, stream>>>(
        AO, wob, d_out, M, D, D, 1);
}